// Round 5
// baseline (114.328 us; speedup 1.0000x reference)
//
#include <hip/hip_runtime.h>
#include <hip/hip_bf16.h>

#define N_PTS   40000
#define N_B     2
#define N_P     128
#define N_K     32
#define N_KC    4
#define N_FEAT  128
#define NQ2     (N_B * N_P * N_K)   // 8192
#define BIGF    3.0e38f

#define QCAP1   512                 // knn1 candidate cap (E[n]=341)
#define QCAP    96                  // knn2 per-query cap (E[n]=42)

#define TAU2    4.0e-3f             // (2.2*r4)^2 ; tau=0.0632
#define TAU1    1.6e-2f             // (2.2*r32)^2 ; tau1=0.1265

// Clean grid: NG=15, h=1/15 > tau2. Bucketized, cap 32 (lambda=11.85, +6sigma).
#define NG      15
#define NCELL   (NG * NG * NG)      // 3375
#define CAPC    32                  // power of 2 (t>>5 / t&31 mapping)

// Noisy grid: NG1=7, h=1/7=0.1429 > tau1=0.1265 -> 27-cell walk is exact.
#define NG1     7
#define NCELL1  (NG1 * NG1 * NG1)   // 343
#define CAP1N   192                 // lambda=116.6, +7sigma

#define GB_BLK  20                  // build blocks per batch per cloud
#define GB_PER  (N_PTS / GB_BLK)    // 2000 pts per block

#define NLOSSB  2048                // loss blocks (4 waves each = 8192 queries)

// Globals (zero-init at load; final_kernel resets counters for the next call).
__device__ int    g_sidx[N_P];
__device__ int    g_fidx[NQ2];
__device__ int    g_ncnt[N_B * NCELL1];               // noisy bucket counts
__device__ float4 g_npts[N_B * NCELL1 * CAP1N];       // noisy buckets (x,y,z,idx) 2.1 MB
__device__ int    g_ccnt[N_B * NCELL];                // clean bucket counts
__device__ float4 g_cpts[N_B * NCELL * CAPC];         // clean buckets (x,y,z,pp) 3.5 MB
__device__ int    g_cpidx[N_B * NCELL * CAPC];        // clean original indices
__device__ float  g_lploss[NLOSSB];                   // per-block partials
__device__ float  g_M3[9];
__device__ float  g_WxS[9];

__device__ __forceinline__ int clampi(int v, int lo, int hi) { return v < lo ? lo : (v > hi ? hi : v); }

__device__ __forceinline__ unsigned long long packkey(float d, int idx)
{
    unsigned int u = __float_as_uint(d);
    u ^= (u >> 31) ? 0xFFFFFFFFu : 0x80000000u;
    return ((unsigned long long)u << 32) | (unsigned int)idx;
}

__device__ __forceinline__ int cell_of(float x, float y, float z)
{
    const int cx = clampi((int)(x * NG), 0, NG - 1);
    const int cy = clampi((int)(y * NG), 0, NG - 1);
    const int cz = clampi((int)(z * NG), 0, NG - 1);
    return cx + NG * (cy + NG * cz);
}

// ---------------------------------------------------------------------------
// Launch A: build BOTH bucket grids in one scatter pass (no hist, no scan)
// + sidx/M3 decode. Blocks: [0,40) noisy buckets, [40,80) clean buckets,
// 80 = decode. NOTE (R1 lesson): no in-kernel cross-block finishers —
// per-block __threadfence on gfx950 is a whole-L2 wb/inv storm.
// ---------------------------------------------------------------------------
__global__ __launch_bounds__(256) void build_kernel(
    const float* __restrict__ noisy,
    const float* __restrict__ clean,
    const void*  __restrict__ sidx_raw,
    const float* __restrict__ Wf,
    const float* __restrict__ Wx,
    const float* __restrict__ Wc)
{
    __shared__ int flags[4];
    const int blk = blockIdx.x;
    const int tid = threadIdx.x;

    if (blk < N_B * GB_BLK) {
        // ------- noisy bucket scatter (NG1 grid, idx packed in w) -------
        const int bb = blk / GB_BLK;
        const int sb = blk % GB_BLK;
        const float* nb = noisy + bb * (N_PTS * 3);
        const int j0 = sb * GB_PER;
        for (int j = j0 + tid; j < j0 + GB_PER; j += 256) {
            const float x = nb[j * 3 + 0], y = nb[j * 3 + 1], z = nb[j * 3 + 2];
            const int cx = clampi((int)(x * NG1), 0, NG1 - 1);
            const int cy = clampi((int)(y * NG1), 0, NG1 - 1);
            const int cz = clampi((int)(z * NG1), 0, NG1 - 1);
            const int ci = bb * NCELL1 + cx + NG1 * (cy + NG1 * cz);
            const int pos = atomicAdd(&g_ncnt[ci], 1);
            if (pos < CAP1N)
                g_npts[ci * CAP1N + pos] = make_float4(x, y, z, __int_as_float(j));
        }
    } else if (blk < 2 * N_B * GB_BLK) {
        // ------- clean bucket scatter (NG grid, pp in w; idx parallel) -------
        const int blk2 = blk - N_B * GB_BLK;
        const int bb = blk2 / GB_BLK;
        const int sb = blk2 % GB_BLK;
        const float* cb = clean + bb * (N_PTS * 3);
        const int j0 = sb * GB_PER;
        for (int j = j0 + tid; j < j0 + GB_PER; j += 256) {
            const float x = cb[j * 3 + 0], y = cb[j * 3 + 1], z = cb[j * 3 + 2];
            const int ci = bb * NCELL + cell_of(x, y, z);
            const int pos = atomicAdd(&g_ccnt[ci], 1);
            if (pos < CAPC) {
                const float pp = fmaf(z, z, fmaf(y, y, x * x));
                g_cpts[ci * CAPC + pos]  = make_float4(x, y, z, pp);
                g_cpidx[ci * CAPC + pos] = j;
            }
        }
    } else {
        // ------- hoisted M3/Wx + sidx dtype-vote decode (verbatim) -------
        if (tid < 9) {
            const int d = tid / 3, e = tid % 3;
            float acc = 0.0f;
            for (int f0 = 0; f0 < N_FEAT; ++f0)
                acc += Wf[d * N_FEAT + f0] * Wc[f0 * 3 + e];
            g_M3[tid]  = acc;
            g_WxS[tid] = Wx[tid];
        }
        if (tid == 0) { flags[0] = 1; flags[1] = 1; flags[2] = 1; flags[3] = 1; }
        __syncthreads();
        const int*       p32 = (const int*)sidx_raw;
        const long long* p64 = (const long long*)sidx_raw;
        const float*     pf  = (const float*)sidx_raw;
        if (tid < 128) {
            const int       v32 = p32[tid];
            const long long v64 = p64[tid];
            const float     vf  = pf[tid];
            if (!(v32 >= 0 && v32 < N_PTS)) atomicAnd(&flags[0], 0);
            if ((tid & 1) && v32 != 0)      atomicAnd(&flags[1], 0);
            if (!(v64 >= 0 && v64 < N_PTS)) atomicAnd(&flags[2], 0);
            if (!(vf >= 0.0f && vf < (float)N_PTS && vf == floorf(vf))) atomicAnd(&flags[3], 0);
        }
        __syncthreads();
        if (tid < 128) {
            int si;
            if (flags[0] && !(flags[1] && flags[2])) si = p32[tid];
            else if (flags[2])                       si = (int)p64[tid];
            else if (flags[3])                       si = (int)(pf[tid] + 0.5f);
            else                                     si = 0;
            g_sidx[tid] = clampi(si, 0, N_PTS - 1);
        }
    }
}

// ---------------------------------------------------------------------------
// Launch B: knn1 via noisy bucket grid. One block per query: 27-cell walk
// (provably superset of {d2<TAU1} since h>tau1), tau-append to LDS keys,
// fused 512-key bitonic sort. Candidate set + sort keys bit-identical to
// the old scan+merge pair; overflow/underflow -> exact brute fallback.
// ---------------------------------------------------------------------------
__global__ __launch_bounds__(256) void knn1_grid_kernel(
    const float* __restrict__ noisy)
{
    __shared__ unsigned long long keys[2048];   // 16 KB (sort + fallback)
    __shared__ int lcnt, ovf;
    const int qb   = blockIdx.x;
    const int tid  = threadIdx.x;
    const int wv   = tid >> 6;
    const int lane = tid & 63;
    const int b    = qb >> 7;
    const int p    = qb & 127;
    const float* nb = noisy + b * (N_PTS * 3);

    if (tid == 0) { lcnt = 0; ovf = 0; }
    const int si = g_sidx[p];
    const float qx = nb[si * 3 + 0];
    const float qy = nb[si * 3 + 1];
    const float qz = nb[si * 3 + 2];
    const int c1x = clampi((int)(qx * NG1), 0, NG1 - 1);
    const int c1y = clampi((int)(qy * NG1), 0, NG1 - 1);
    const int c1z = clampi((int)(qz * NG1), 0, NG1 - 1);
    __syncthreads();

    // wave wv handles cells wv, wv+4, ... of the 27-neighborhood
    for (int i = wv; i < 27; i += 4) {
        const int cx = c1x + (i % 3) - 1;
        const int cy = c1y + ((i / 3) % 3) - 1;
        const int cz = c1z + (i / 9) - 1;
        if (cx < 0 || cx >= NG1 || cy < 0 || cy >= NG1 || cz < 0 || cz >= NG1) continue;
        const int ci  = b * NCELL1 + cx + NG1 * (cy + NG1 * cz);
        const int cnt = g_ncnt[ci];
        if (cnt > CAP1N && lane == 0) ovf = 1;
        const int n = (cnt < CAP1N) ? cnt : CAP1N;
        const float4* bp = &g_npts[ci * CAP1N];
        for (int k = lane; k < n; k += 64) {
            const float4 pt = bp[k];
            const float dx = qx - pt.x;
            const float dy = qy - pt.y;
            const float dz = qz - pt.z;
            const float d2 = fmaf(dz, dz, fmaf(dy, dy, dx * dx));
            if (d2 < TAU1) {
                const int slot = atomicAdd(&lcnt, 1);
                if (slot < QCAP1)
                    keys[slot] = ((unsigned long long)__float_as_uint(d2) << 32)
                               | (unsigned int)__float_as_int(pt.w);
            }
        }
    }
    __syncthreads();

    const int cnt = lcnt;
    if (!ovf && cnt >= 32 && cnt <= QCAP1) {
        for (int i = tid; i < QCAP1; i += 256)
            if (i >= cnt) keys[i] = ~0ULL;
        __syncthreads();
        for (int k = 2; k <= QCAP1; k <<= 1) {
            for (int jj = k >> 1; jj > 0; jj >>= 1) {
                const int i = ((tid & ~(jj - 1)) << 1) | (tid & (jj - 1));
                const int partner = i | jj;
                const bool asc = ((i & k) == 0);
                const unsigned long long a = keys[i];
                const unsigned long long c = keys[partner];
                if ((a > c) == asc) { keys[i] = c; keys[partner] = a; }
                __syncthreads();
            }
        }
    } else {
        // ------- exact brute fallback (verbatim from old merge kernel) -------
        float bd[8]; int bi[8];
#pragma unroll
        for (int i = 0; i < 8; ++i) { bd[i] = BIGF; bi[i] = 0x7fffffff; }
        for (int j = tid; j < N_PTS; j += 256) {
            const float dx = qx - nb[j * 3 + 0];
            const float dy = qy - nb[j * 3 + 1];
            const float dz = qz - nb[j * 3 + 2];
            const float d2 = fmaf(dz, dz, fmaf(dy, dy, dx * dx));
            if (d2 < bd[7]) {
                bd[7] = d2; bi[7] = j;
#pragma unroll
                for (int t = 7; t > 0; --t) {
                    if (bd[t] < bd[t - 1]) {
                        float td = bd[t]; bd[t] = bd[t - 1]; bd[t - 1] = td;
                        int   ti = bi[t]; bi[t] = bi[t - 1]; bi[t - 1] = ti;
                    }
                }
            }
        }
#pragma unroll
        for (int t = 0; t < 8; ++t)
            keys[tid * 8 + t] = ((unsigned long long)__float_as_uint(bd[t]) << 32)
                              | (unsigned int)bi[t];
        __syncthreads();
        for (int k = 2; k <= 2048; k <<= 1) {
            for (int jj = k >> 1; jj > 0; jj >>= 1) {
#pragma unroll
                for (int base = 0; base < 2048; base += 256) {
                    const int i = base + tid;
                    const int partner = i ^ jj;
                    if (partner > i) {
                        const bool asc = ((i & k) == 0);
                        const unsigned long long a = keys[i];
                        const unsigned long long c = keys[partner];
                        if ((a > c) == asc) { keys[i] = c; keys[partner] = a; }
                    }
                }
                __syncthreads();
            }
        }
    }

    if (tid < 32) {
        const int idx = (int)(keys[tid] & 0xFFFFFFFFull);
        g_fidx[qb * 32 + tid] = clampi(idx, 0, N_PTS - 1);
    }
}

// ---------------------------------------------------------------------------
// Launch C: fused knn2 + loss. Walk = 27 fixed-cap buckets, all 64 lanes
// strip-mine (cell = t>>5, slot = t&31). FIX (R3 bug): BOTH cross-lane
// shuffles hoisted to iteration scope — __shfl from inside a divergent
// branch reads a possibly-inactive source lane (ds_bpermute drops the
// push of EXEC=0 lanes) and returned garbage bucket bases.
// ---------------------------------------------------------------------------
__global__ __launch_bounds__(256) void knn2_loss_kernel(
    const float* __restrict__ noisy,
    const float* __restrict__ clean)
{
    __shared__ float2 buf[4][QCAP];    // 3 KB
    __shared__ int    bcnt[4];
    __shared__ float  red[4];
    const int tid  = threadIdx.x;
    const int wv   = tid >> 6;
    const int lane = tid & 63;
    const int g    = blockIdx.x * 4 + wv;
    const int b    = g >> 12;
    const int p    = (g >> 5) & 127;
    const float* nb = noisy + b * (N_PTS * 3);
    const float* cb = clean + b * (N_PTS * 3);

    if (lane == 0) bcnt[wv] = 0;

    const int fid = clampi(g_fidx[g], 0, N_PTS - 1);
    const float fx = nb[fid * 3 + 0];
    const float fy = nb[fid * 3 + 1];
    const float fz = nb[fid * 3 + 2];
    const float fm2x = -2.0f * fx, fm2y = -2.0f * fy, fm2z = -2.0f * fz;
    const float ff = fmaf(fz, fz, fmaf(fy, fy, fx * fx));
    const float taup = TAU2 - ff;

    const int cfx = clampi((int)(fx * NG), 0, NG - 1);
    const int cfy = clampi((int)(fy * NG), 0, NG - 1);
    const int cfz = clampi((int)(fz * NG), 0, NG - 1);

    int cnt_l = 0, base_l = 0;
    if (lane < 27) {
        const int cx = cfx + (lane % 3) - 1;
        const int cy = cfy + ((lane / 3) % 3) - 1;
        const int cz = cfz + (lane / 9) - 1;
        if (cx >= 0 && cx < NG && cy >= 0 && cy < NG && cz >= 0 && cz < NG) {
            const int ci = b * NCELL + cx + NG * (cy + NG * cz);
            cnt_l  = g_ccnt[ci];
            base_l = ci * CAPC;
        }
    }
    const unsigned long long ovfm = __ballot(lane < 27 && cnt_l > CAPC);
    if (ovfm == 0ULL) {
        for (int t = lane; t < 27 * CAPC; t += 64) {
            const int ci = t >> 5;          // CAPC == 32
            const int sl = t & (CAPC - 1);
            const int cc  = __shfl(cnt_l, ci);   // full-iteration scope:
            const int cb2 = __shfl(base_l, ci);  // source lanes provably active
            if (sl < cc) {
                const float4 pt = g_cpts[cb2 + sl];
                const float d2 = fmaf(fm2x, pt.x, fmaf(fm2y, pt.y, fmaf(fm2z, pt.z, pt.w)));
                if (d2 < taup) {
                    const int slot = atomicAdd(&bcnt[wv], 1);
                    if (slot < QCAP)
                        buf[wv][slot] = make_float2(d2, __int_as_float(g_cpidx[cb2 + sl]));
                }
            }
        }
    } else if (lane == 0) {
        bcnt[wv] = QCAP + 1000;             // bucket overflow -> exact fallback
    }
    __syncthreads();

    // ------- loss: wave butterfly top-4 from the LDS list; exact fallback -------
    const int cnt = bcnt[wv];
    int nn[4];

    if (cnt >= 4 && cnt <= QCAP) {
        unsigned long long e0 = ~0ULL, e1 = ~0ULL;
        if (lane < cnt) {
            const float2 a = buf[wv][lane];
            e0 = packkey(a.x, __float_as_int(a.y));
        }
        if (lane + 64 < cnt) {
            const float2 a = buf[wv][lane + 64];
            e1 = packkey(a.x, __float_as_int(a.y));
        }
        if (e1 < e0) { unsigned long long t = e0; e0 = e1; e1 = t; }

        int c = 0;
#pragma unroll
        for (int r = 0; r < 4; ++r) {
            const unsigned long long h = (c == 0) ? e0 : ((c == 1) ? e1 : ~0ULL);
            unsigned long long m = h;
#pragma unroll
            for (int off = 32; off; off >>= 1) {
                const unsigned long long o = __shfl_xor(m, off);
                if (o < m) m = o;
            }
            if (h == m) c++;
            nn[r] = (int)(m & 0xFFFFFFFFull);
        }
    } else {
        float bd[4]; int bi[4];
#pragma unroll
        for (int t = 0; t < 4; ++t) { bd[t] = BIGF; bi[t] = 0x7fffffff; }
        for (int j = lane; j < N_PTS; j += 64) {
            const float dx = fx - cb[j * 3 + 0];
            const float dy = fy - cb[j * 3 + 1];
            const float dz = fz - cb[j * 3 + 2];
            const float d2 = fmaf(dz, dz, fmaf(dy, dy, dx * dx));
            if (d2 < bd[3]) {
                bd[3] = d2; bi[3] = j;
#pragma unroll
                for (int t = 3; t > 0; --t) {
                    if (bd[t] < bd[t - 1]) {
                        float td = bd[t]; bd[t] = bd[t - 1]; bd[t - 1] = td;
                        int   ti = bi[t]; bi[t] = bi[t - 1]; bi[t - 1] = ti;
                    }
                }
            }
        }
        int cur = 0;
        for (int r = 0; r < 4; ++r) {
            float v  = (cur < 4) ? bd[cur] : BIGF;
            int   vi = (cur < 4) ? bi[cur] : 0x7fffffff;
            int   who = lane;
#pragma unroll
            for (int off = 32; off; off >>= 1) {
                const float v2  = __shfl_down(v, off);
                const int   vi2 = __shfl_down(vi, off);
                const int   w2  = __shfl_down(who, off);
                if (v2 < v || (v2 == v && vi2 < vi)) { v = v2; vi = vi2; who = w2; }
            }
            const int bvi = __shfl(vi, 0);
            const int bwh = __shfl(who, 0);
            nn[r] = bvi;
            if (lane == bwh) cur++;
        }
    }

    float t2 = 0.0f;
    if (lane == 0) {
        const int si = g_sidx[p];
        const float qx = nb[si * 3 + 0], qy = nb[si * 3 + 1], qz = nb[si * 3 + 2];
        const int n0 = clampi(nn[0], 0, N_PTS - 1), n1 = clampi(nn[1], 0, N_PTS - 1);
        const int n2 = clampi(nn[2], 0, N_PTS - 1), n3 = clampi(nn[3], 0, N_PTS - 1);
        const float mx = 0.25f * (cb[n0*3+0] + cb[n1*3+0] + cb[n2*3+0] + cb[n3*3+0]);
        const float my = 0.25f * (cb[n0*3+1] + cb[n1*3+1] + cb[n2*3+1] + cb[n3*3+1]);
        const float mz = 0.25f * (cb[n0*3+2] + cb[n1*3+2] + cb[n2*3+2] + cb[n3*3+2]);

        const float gx = mx - fx, gy = my - fy, gz = mz - fz;
        const float rx = fx - qx, ry = fy - qy, rz = fz - qz;
        const float ex = rx * g_WxS[0] + ry * g_WxS[3] + rz * g_WxS[6] + qx * g_M3[0] + qy * g_M3[3] + qz * g_M3[6];
        const float ey = rx * g_WxS[1] + ry * g_WxS[4] + rz * g_WxS[7] + qx * g_M3[1] + qy * g_M3[4] + qz * g_M3[7];
        const float ez = rx * g_WxS[2] + ry * g_WxS[5] + rz * g_WxS[8] + qx * g_M3[2] + qy * g_M3[5] + qz * g_M3[8];
        const float dx = ex - gx, dy = ey - gy, dz = ez - gz;
        t2 = dx * dx + dy * dy + dz * dz;
    }

    if (lane == 0) red[wv] = t2;
    __syncthreads();
    if (tid == 0) g_lploss[blockIdx.x] = (red[0] + red[1]) + (red[2] + red[3]);
}

// ---------------------------------------------------------------------------
// Launch D: block 0 sums the 2048 partials; blocks 1-2 reset the bucket
// counters for the next call (runs after all consumers).
// ---------------------------------------------------------------------------
__global__ __launch_bounds__(256) void final_kernel(float* __restrict__ out)
{
    __shared__ float red[4];
    const int tid = threadIdx.x;

    if (blockIdx.x == 1) {
        for (int i = tid; i < N_B * NCELL; i += 256) g_ccnt[i] = 0;
        return;
    }
    if (blockIdx.x == 2) {
        for (int i = tid; i < N_B * NCELL1; i += 256) g_ncnt[i] = 0;
        return;
    }

    float v = 0.0f;
    for (int i = tid; i < NLOSSB; i += 256) v += g_lploss[i];
#pragma unroll
    for (int off = 32; off; off >>= 1) v += __shfl_down(v, off);
    if ((tid & 63) == 0) red[tid >> 6] = v;
    __syncthreads();
    if (tid == 0) out[0] = ((red[0] + red[1]) + (red[2] + red[3])) * (50.0f / 8192.0f);
}

extern "C" void kernel_launch(void* const* d_in, const int* in_sizes, int n_in,
                              void* d_out, int out_size, void* d_ws, size_t ws_size,
                              hipStream_t stream)
{
    (void)d_ws; (void)ws_size; (void)in_sizes; (void)n_in; (void)out_size;

    const float* noisy = (const float*)d_in[0];
    const float* clean = (const float*)d_in[1];
    const float* Wf    = (const float*)d_in[3];
    const float* Wx    = (const float*)d_in[4];
    const float* Wc    = (const float*)d_in[5];

    // A: noisy buckets (40) + clean buckets (40) + decode (1)
    build_kernel<<<2 * N_B * GB_BLK + 1, 256, 0, stream>>>(noisy, clean, d_in[2], Wf, Wx, Wc);
    // B: knn1 via noisy grid, fused sort (256 blocks, one per query)
    knn1_grid_kernel<<<256, 256, 0, stream>>>(noisy);
    // C: fused knn2 + loss (2048 blocks)
    knn2_loss_kernel<<<NLOSSB, 256, 0, stream>>>(noisy, clean);
    // D: final reduction + counter resets (3 blocks)
    final_kernel<<<3, 256, 0, stream>>>((float*)d_out);
}